// Round 3
// baseline (324.326 us; speedup 1.0000x reference)
//
#include <hip/hip_runtime.h>
#include <hip/hip_fp8.h>

typedef __attribute__((ext_vector_type(8))) short short8;
typedef __attribute__((ext_vector_type(4))) float floatx4;
typedef __attribute__((ext_vector_type(8))) int int8v;
typedef __attribute__((ext_vector_type(4))) int int4v;

#define LDS_PTR(x) ((__attribute__((address_space(3))) unsigned int*)(x))
#define GLB_PTR(x) ((const __attribute__((address_space(1))) unsigned int*)(x))

__device__ __forceinline__ unsigned short f2bf(float f) {
    unsigned int u = __float_as_uint(f);
    unsigned int r = (u + 0x7FFFu + ((u >> 16) & 1u)) >> 16;
    return (unsigned short)r;
}
__device__ __forceinline__ unsigned char f2fp8(float f) {
    __hip_fp8_e4m3 v(f);
    return (unsigned char)v.__x;
}
__device__ __forceinline__ float fp82f(unsigned int u) {
    __hip_fp8_e4m3 v;
    v.__x = (__hip_fp8_storage_t)(u & 0xFF);
    return (float)v;
}

// ---------------------------------------------------------------------------
// Fused post-side prep (one read of post_spikes & post_trace):
//   out_post_trace = S + dp*T (fp32, native)
//   At[p][k]   = fp8(S^T)   k in [0,B)      (RAW spikes)
//   At[p][B+k] = fp8(T^T)                   (RAW trace — dp folded into s)
// ---------------------------------------------------------------------------
__global__ __launch_bounds__(256) void prep_post_kernel(
    const float* __restrict__ S, const float* __restrict__ T,
    float* __restrict__ traceOut, unsigned char* __restrict__ At,
    int C, int K2, int Bsz, float dp)
{
    __shared__ float sT[64][65];
    __shared__ float tT[64][65];
    const int t = threadIdx.x;
    const int r0 = blockIdx.y * 64, c0 = blockIdx.x * 64;
#pragma unroll
    for (int i = 0; i < 4; ++i) {
        int rl = (t >> 4) + i * 16;
        int cl = (t & 15) * 4;
        size_t g = (size_t)(r0 + rl) * C + c0 + cl;
        float4 s4 = *(const float4*)&S[g];
        float4 t4 = *(const float4*)&T[g];
        float4 o;
        o.x = fmaf(t4.x, dp, s4.x); o.y = fmaf(t4.y, dp, s4.y);
        o.z = fmaf(t4.z, dp, s4.z); o.w = fmaf(t4.w, dp, s4.w);
        *(float4*)&traceOut[g] = o;
        sT[rl][cl + 0] = s4.x; sT[rl][cl + 1] = s4.y;
        sT[rl][cl + 2] = s4.z; sT[rl][cl + 3] = s4.w;
        tT[rl][cl + 0] = t4.x; tT[rl][cl + 1] = t4.y;
        tT[rl][cl + 2] = t4.z; tT[rl][cl + 3] = t4.w;
    }
    __syncthreads();
#pragma unroll
    for (int i = 0; i < 4; ++i) {
        int cl = (t >> 4) + i * 16;
        int rl = (t & 15) * 4;
        uchar4 a, b;
        a.x = f2fp8(sT[rl + 0][cl]); a.y = f2fp8(sT[rl + 1][cl]);
        a.z = f2fp8(sT[rl + 2][cl]); a.w = f2fp8(sT[rl + 3][cl]);
        b.x = f2fp8(tT[rl + 0][cl]); b.y = f2fp8(tT[rl + 1][cl]);
        b.z = f2fp8(tT[rl + 2][cl]); b.w = f2fp8(tT[rl + 3][cl]);
        *(uchar4*)&At[(size_t)(c0 + cl) * K2 + r0 + rl] = a;
        *(uchar4*)&At[(size_t)(c0 + cl) * K2 + Bsz + r0 + rl] = b;
    }
}

// ---------------------------------------------------------------------------
// Fused pre-side prep:
//   out_pre_trace = S + dp*T (fp32, native);  preBf = bf16(S) (native)
//   Bt[q][k]   = fp8(T^T)       (RAW pre_trace)
//   Bt[q][B+k] = fp8(-S^T)      (negated pre_spikes — sign folded)
// ---------------------------------------------------------------------------
__global__ __launch_bounds__(256) void prep_pre_kernel(
    const float* __restrict__ S, const float* __restrict__ T,
    float* __restrict__ traceOut, unsigned char* __restrict__ Bt,
    unsigned short* __restrict__ preBf,
    int C, int K2, int Bsz, float dp)
{
    __shared__ float sT[64][65];
    __shared__ float tT[64][65];
    const int t = threadIdx.x;
    const int r0 = blockIdx.y * 64, c0 = blockIdx.x * 64;
#pragma unroll
    for (int i = 0; i < 4; ++i) {
        int rl = (t >> 4) + i * 16;
        int cl = (t & 15) * 4;
        size_t g = (size_t)(r0 + rl) * C + c0 + cl;
        float4 s4 = *(const float4*)&S[g];
        float4 t4 = *(const float4*)&T[g];
        float4 o;
        o.x = fmaf(t4.x, dp, s4.x); o.y = fmaf(t4.y, dp, s4.y);
        o.z = fmaf(t4.z, dp, s4.z); o.w = fmaf(t4.w, dp, s4.w);
        *(float4*)&traceOut[g] = o;
        ushort4 pb = { f2bf(s4.x), f2bf(s4.y), f2bf(s4.z), f2bf(s4.w) };
        *(ushort4*)&preBf[g] = pb;
        sT[rl][cl + 0] = s4.x; sT[rl][cl + 1] = s4.y;
        sT[rl][cl + 2] = s4.z; sT[rl][cl + 3] = s4.w;
        tT[rl][cl + 0] = t4.x; tT[rl][cl + 1] = t4.y;
        tT[rl][cl + 2] = t4.z; tT[rl][cl + 3] = t4.w;
    }
    __syncthreads();
#pragma unroll
    for (int i = 0; i < 4; ++i) {
        int cl = (t >> 4) + i * 16;
        int rl = (t & 15) * 4;
        uchar4 a, b;
        a.x = f2fp8(tT[rl + 0][cl]); a.y = f2fp8(tT[rl + 1][cl]);
        a.z = f2fp8(tT[rl + 2][cl]); a.w = f2fp8(tT[rl + 3][cl]);
        b.x = f2fp8(-sT[rl + 0][cl]); b.y = f2fp8(-sT[rl + 1][cl]);
        b.z = f2fp8(-sT[rl + 2][cl]); b.w = f2fp8(-sT[rl + 3][cl]);
        *(uchar4*)&Bt[(size_t)(c0 + cl) * K2 + r0 + rl] = a;
        *(uchar4*)&Bt[(size_t)(c0 + cl) * K2 + Bsz + r0 + rl] = b;
    }
}

// ---------------------------------------------------------------------------
// Rate EMA from fp8-transposed post_spikes rows (At, k-contiguous).
// ---------------------------------------------------------------------------
__global__ __launch_bounds__(256) void rate_kernel(
    const unsigned char* __restrict__ At, const float* __restrict__ rr,
    float* __restrict__ new_rate, int K2, int Bsz)
{
    const int w = threadIdx.x >> 6, l = threadIdx.x & 63;
    const int p = blockIdx.x * 4 + w;
    const unsigned char* row = At + (size_t)p * K2;
    float s = 0.f;
    for (int k = l * 16; k < Bsz; k += 1024) {
        int4v v = *(const int4v*)&row[k];
#pragma unroll
        for (int wd = 0; wd < 4; ++wd) {
            unsigned int u = (unsigned int)v[wd];
            s += fp82f(u) + fp82f(u >> 8) + fp82f(u >> 16) + fp82f(u >> 24);
        }
    }
#pragma unroll
    for (int off = 32; off > 0; off >>= 1) s += __shfl_xor(s, off, 64);
    if (l == 0)
        new_rate[p] = rr[p] * 0.99f + 0.01f * (s / (float)Bsz);
}

// ---------------------------------------------------------------------------
// MX-fp8 dw GEMM: dw[p][q] = s * sum_k A[p][k]*B[q][k]  (both K-major fp8)
// 128x128 tile, BK=128, mfma_scale_f32_16x16x128_f8f6f4, unit e8m0 scales.
// NEW (R3): Wold tile (64KB) + homeo terms preloaded into registers BEFORE
// the K-loop, so the epilogue's HBM fetch streams concurrently with compute
// (K-loop generates ~no HBM traffic — At/Bt are L3-resident). Epilogue is
// write-only: LDS-transposed coalesced stores of outF (fp32) + outBf (bf16).
// ---------------------------------------------------------------------------
__global__ __launch_bounds__(256) void dw_fp8_kernel(
    const unsigned char* __restrict__ A, const unsigned char* __restrict__ B,
    int K, int N, float s,
    const float* __restrict__ Wold, const float* __restrict__ rr,
    float* __restrict__ outF, unsigned short* __restrict__ outBf)
{
    constexpr int BM = 128, BN = 128, BK = 128;
    __shared__ unsigned char smem[65536];   // 2x(lA 16K) + 2x(lB 16K) | f32 out tile

    const int t = threadIdx.x;
    const int l = t & 63;
    const int w = t >> 6;
    const int wm = w >> 1, wn = w & 1;
    const int bm = blockIdx.y, bn = blockIdx.x;

    floatx4 acc[4][4] = {};

    auto stage = [&](int buf, int k0) {
        unsigned char* la = smem + buf * 16384;
        unsigned char* lb = smem + 32768 + buf * 16384;
#pragma unroll
        for (int i = 0; i < 4; ++i) {
            int ci = i * 256 + t;            // 16B chunk index (lane-linear)
            int r = ci >> 3, sc = ci & 7;
            int g = sc ^ (r & 7);            // swizzled source sub-chunk
            const unsigned char* gpA = A + (size_t)(bm * BM + r) * K + k0 + g * 16;
            __builtin_amdgcn_global_load_lds(GLB_PTR(gpA),
                LDS_PTR(la + ci * 16), 16, 0, 0);
            const unsigned char* gpB = B + (size_t)(bn * BN + r) * K + k0 + g * 16;
            __builtin_amdgcn_global_load_lds(GLB_PTR(gpB),
                LDS_PTR(lb + ci * 16), 16, 0, 0);
        }
    };

    stage(0, 0);

    // --- preload Wold tile + homeo terms into registers (overlaps K-loop) ---
    const int pBase = bm * BM;
    const int qBase = bn * BN;
    float4 wold[16];
    float hp[16];
#pragma unroll
    for (int k = 0; k < 16; ++k) {
        const int ci = k * 256 + t;          // same mapping as epilogue
        const int row = ci >> 5;
        const int cc = (ci & 31) * 4;
        wold[k] = *(const float4*)&Wold[(size_t)(pBase + row) * N + qBase + cc];
        hp[k] = -0.001f * (rr[pBase + row] - 0.1f);
    }

    __syncthreads();                 // prologue drain

    const int nT = K / BK;
    int cur = 0;
    for (int tt = 0; tt < nT; ++tt) {
        if (tt + 1 < nT) stage(cur ^ 1, (tt + 1) * BK);   // prefetch next tile

        const unsigned char* la = smem + cur * 16384;
        const unsigned char* lb = smem + 32768 + cur * 16384;
        const int c = l >> 4;      // k-quad: covers k bytes [c*32, c*32+32)
        const int m = l & 15;
        int8v af[4], bf[4];
#pragma unroll
        for (int i = 0; i < 4; ++i) {
            int ra = wm * 64 + i * 16 + m;
            int s0 = (2 * c) ^ (ra & 7), s1 = (2 * c + 1) ^ (ra & 7);
            int4v lo = *(const int4v*)&la[ra * BK + s0 * 16];
            int4v hi = *(const int4v*)&la[ra * BK + s1 * 16];
            af[i][0] = lo[0]; af[i][1] = lo[1]; af[i][2] = lo[2]; af[i][3] = lo[3];
            af[i][4] = hi[0]; af[i][5] = hi[1]; af[i][6] = hi[2]; af[i][7] = hi[3];
        }
#pragma unroll
        for (int j = 0; j < 4; ++j) {
            int rb = wn * 64 + j * 16 + m;
            int s0 = (2 * c) ^ (rb & 7), s1 = (2 * c + 1) ^ (rb & 7);
            int4v lo = *(const int4v*)&lb[rb * BK + s0 * 16];
            int4v hi = *(const int4v*)&lb[rb * BK + s1 * 16];
            bf[j][0] = lo[0]; bf[j][1] = lo[1]; bf[j][2] = lo[2]; bf[j][3] = lo[3];
            bf[j][4] = hi[0]; bf[j][5] = hi[1]; bf[j][6] = hi[2]; bf[j][7] = hi[3];
        }
#pragma unroll
        for (int i = 0; i < 4; ++i)
#pragma unroll
            for (int j = 0; j < 4; ++j)
                acc[i][j] = __builtin_amdgcn_mfma_scale_f32_16x16x128_f8f6f4(
                    af[i], bf[j], acc[i][j], 0, 0, 0, 0x7f, 0, 0x7f);

        asm volatile("s_waitcnt vmcnt(0)" ::: "memory");
        __builtin_amdgcn_s_barrier();
        cur ^= 1;
    }

    // ---- coalesced, write-only epilogue: acc -> LDS f32 tile -> global ----
    __syncthreads();
    float* sOut = (float*)smem;      // 128 x 128 f32 = 64KB
#pragma unroll
    for (int i = 0; i < 4; ++i)
#pragma unroll
        for (int r = 0; r < 4; ++r) {
            const int row = wm * 64 + i * 16 + (l >> 4) * 4 + r;
#pragma unroll
            for (int j = 0; j < 4; ++j) {
                const int col = wn * 64 + j * 16 + (l & 15);
                sOut[row * 128 + col] = acc[i][j][r];
            }
        }
    __syncthreads();

#pragma unroll
    for (int k = 0; k < 16; ++k) {
        const int ci = k * 256 + t;          // float4 chunk index 0..4095
        const int row = ci >> 5;             // 0..127
        const int cc = (ci & 31) * 4;        // 0..124
        const size_t idx = (size_t)(pBase + row) * N + qBase + cc;
        float4 a4 = *(const float4*)&sOut[ci * 4];
        float4 v;
        v.x = fminf(fmaxf(fmaf(s, a4.x, wold[k].x + hp[k]), 0.f), 1.f);
        v.y = fminf(fmaxf(fmaf(s, a4.y, wold[k].y + hp[k]), 0.f), 1.f);
        v.z = fminf(fmaxf(fmaf(s, a4.z, wold[k].z + hp[k]), 0.f), 1.f);
        v.w = fminf(fmaxf(fmaf(s, a4.w, wold[k].w + hp[k]), 0.f), 1.f);
        *(float4*)&outF[idx] = v;
        ushort4 b4 = { f2bf(v.x), f2bf(v.y), f2bf(v.z), f2bf(v.w) };
        *(ushort4*)&outBf[idx] = b4;
    }
}

// ---------------------------------------------------------------------------
// BT-form bf16 MFMA GEMM (current = pre @ W^T).
// R3: BM=64, BN=128, BK=64 -> grid 512 blocks (2 resident/CU, was 1/CU at
// 128x128 since M=1024 caps the grid at 256). LDS 48KB double-buffered.
// Per wave: 32x64 output, 16 MFMA per K-step. Coalesced epilogue via LDS.
// ---------------------------------------------------------------------------
__global__ __launch_bounds__(256) void mfma_gemm_bt(
    const unsigned short* __restrict__ A,
    const unsigned short* __restrict__ Bm,
    int K, int N, float* __restrict__ outF)
{
    constexpr int BM = 64, BN = 128, BK = 64;
    __shared__ unsigned char smem[49152];   // 2 bufs x (lA 8K + lB 16K); f32 tile 32K

    const int t = threadIdx.x;
    const int l = t & 63;
    const int w = t >> 6;
    const int wm = w >> 1, wn = w & 1;      // 2x2 waves: 32-row half, 64-col half
    const int bm = blockIdx.y, bn = blockIdx.x;

    floatx4 acc[2][4] = {};

    auto stage = [&](int buf, int k0) {
        unsigned short* la = (unsigned short*)(smem + buf * 24576);
        unsigned short* lb = (unsigned short*)(smem + buf * 24576 + 8192);
#pragma unroll
        for (int i = 0; i < 2; ++i) {        // 512 chunks of 16B (64 rows x 8)
            int ci = i * 256 + t;
            int r = ci >> 3, sc = ci & 7;
            int g = sc ^ (r & 7);            // swizzled source sub-chunk
            const unsigned short* gp =
                A + (size_t)(bm * BM + r) * K + k0 + g * 8;
            __builtin_amdgcn_global_load_lds(GLB_PTR(gp),
                LDS_PTR(la + ci * 8), 16, 0, 0);
        }
#pragma unroll
        for (int i = 0; i < 4; ++i) {        // 1024 chunks (128 rows x 8)
            int ci = i * 256 + t;
            int r = ci >> 3, sc = ci & 7;
            int g = sc ^ (r & 7);
            const unsigned short* gp =
                Bm + (size_t)(bn * BN + r) * K + k0 + g * 8;
            __builtin_amdgcn_global_load_lds(GLB_PTR(gp),
                LDS_PTR(lb + ci * 8), 16, 0, 0);
        }
    };

    stage(0, 0);
    __syncthreads();                 // prologue drain

    const int nT = K / BK;
    int cur = 0;
    for (int tt = 0; tt < nT; ++tt) {
        if (tt + 1 < nT) stage(cur ^ 1, (tt + 1) * BK);   // prefetch next tile

        const unsigned short* la = (const unsigned short*)(smem + cur * 24576);
        const unsigned short* lb = (const unsigned short*)(smem + cur * 24576 + 8192);
        const int q = l >> 4;      // 16B chunk within 64B k-slice
        const int m = l & 15;
        short8 af[2][2], bf[4][2];
#pragma unroll
        for (int i = 0; i < 2; ++i) {
            int ra = wm * 32 + i * 16 + m;
#pragma unroll
            for (int ks = 0; ks < 2; ++ks) {
                int c2 = ks * 4 + q;
                af[i][ks] = *(const short8*)&la[ra * BK + ((c2 ^ (ra & 7)) * 8)];
            }
        }
#pragma unroll
        for (int j = 0; j < 4; ++j) {
            int rb = wn * 64 + j * 16 + m;
#pragma unroll
            for (int ks = 0; ks < 2; ++ks) {
                int c2 = ks * 4 + q;
                bf[j][ks] = *(const short8*)&lb[rb * BK + ((c2 ^ (rb & 7)) * 8)];
            }
        }
#pragma unroll
        for (int ks = 0; ks < 2; ++ks)
#pragma unroll
            for (int i = 0; i < 2; ++i)
#pragma unroll
                for (int j = 0; j < 4; ++j)
                    acc[i][j] = __builtin_amdgcn_mfma_f32_16x16x32_bf16(
                        af[i][ks], bf[j][ks], acc[i][j], 0, 0, 0);

        asm volatile("s_waitcnt vmcnt(0)" ::: "memory");
        __builtin_amdgcn_s_barrier();
        cur ^= 1;
    }

    // ---- coalesced epilogue ----
    __syncthreads();
    float* sOut = (float*)smem;      // 64 x 128 f32 = 32KB
#pragma unroll
    for (int i = 0; i < 2; ++i)
#pragma unroll
        for (int r = 0; r < 4; ++r) {
            const int row = wm * 32 + i * 16 + (l >> 4) * 4 + r;
#pragma unroll
            for (int j = 0; j < 4; ++j) {
                const int col = wn * 64 + j * 16 + (l & 15);
                sOut[row * 128 + col] = acc[i][j][r];
            }
        }
    __syncthreads();

    const int pBase = bm * BM;
    const int qBase = bn * BN;
#pragma unroll
    for (int k = 0; k < 8; ++k) {
        const int ci = k * 256 + t;          // float4 chunk 0..2047
        const int row = ci >> 5;             // 0..63
        const int cc = (ci & 31) * 4;
        float4 v = *(const float4*)&sOut[ci * 4];
        *(float4*)&outF[(size_t)(pBase + row) * N + qBase + cc] = v;
    }
}

// ---------------------------------------------------------------------------
extern "C" void kernel_launch(void* const* d_in, const int* in_sizes, int n_in,
                              void* d_out, int out_size, void* d_ws, size_t ws_size,
                              hipStream_t stream)
{
    const float* pre_spikes   = (const float*)d_in[0];
    const float* post_spikes  = (const float*)d_in[1];
    const float* weights      = (const float*)d_in[2];
    const float* pre_trace    = (const float*)d_in[3];
    const float* post_trace   = (const float*)d_in[4];
    const float* running_rate = (const float*)d_in[5];

    const int POST = in_sizes[5];
    const int PRE  = in_sizes[2] / POST;
    const int Bsz  = in_sizes[0] / PRE;
    const int K2   = 2 * Bsz;

    const size_t nCur   = (size_t)Bsz * POST;
    const size_t nW     = (size_t)POST * PRE;
    const size_t nPreT  = (size_t)Bsz * PRE;
    const size_t nPostT = (size_t)Bsz * POST;

    float* out_current    = (float*)d_out;
    float* out_weights    = out_current + nCur;
    float* out_pre_trace  = out_weights + nW;
    float* out_post_trace = out_pre_trace + nPreT;
    float* out_rate       = out_post_trace + nPostT;

    unsigned char* At     = (unsigned char*)d_ws;        // (POST x K2) fp8
    unsigned char* Bt     = At + (size_t)POST * K2;      // (PRE  x K2) fp8
    unsigned short* preBf = (unsigned short*)(Bt + (size_t)PRE * K2); // (B x PRE) bf16
    unsigned short* wBf   = preBf + nPreT;               // (POST x PRE) bf16

    const float dp = 0.95122942450071400910f;            // exp(-1/20)
    const float s  = dp * (0.01f / (float)Bsz);          // A+/-. * dp / B

    // 1) fused prep: traces + fp8 GEMM operands (one read per input)
    prep_post_kernel<<<dim3(POST / 64, Bsz / 64), 256, 0, stream>>>(
        post_spikes, post_trace, out_post_trace, At, POST, K2, Bsz, dp);
    prep_pre_kernel<<<dim3(PRE / 64, Bsz / 64), 256, 0, stream>>>(
        pre_spikes, pre_trace, out_pre_trace, Bt, preBf, PRE, K2, Bsz, dp);

    // 2) rate EMA
    rate_kernel<<<POST / 4, 256, 0, stream>>>(
        At, running_rate, out_rate, K2, Bsz);

    // 3) dw GEMM in MX-fp8 (M=POST, N=PRE, K=2B) + fused w/homeo/clip
    dw_fp8_kernel<<<dim3(PRE / 128, POST / 128), 256, 0, stream>>>(
        At, Bt, K2, PRE, s, weights, running_rate, out_weights, wBf);

    // 4) current GEMM bf16 (M=B, N=POST, K=PRE): pre_spikes @ new_w^T
    mfma_gemm_bt<<<dim3(POST / 128, Bsz / 64), 256, 0, stream>>>(
        preBf, wBf, PRE, POST, out_current);
}

// Round 4
// 297.336 us; speedup vs baseline: 1.0908x; 1.0908x over previous
//
#include <hip/hip_runtime.h>
#include <hip/hip_fp8.h>

typedef __attribute__((ext_vector_type(8))) short short8;
typedef __attribute__((ext_vector_type(4))) float floatx4;
typedef __attribute__((ext_vector_type(8))) int int8v;
typedef __attribute__((ext_vector_type(4))) int int4v;

#define LDS_PTR(x) ((__attribute__((address_space(3))) unsigned int*)(x))
#define GLB_PTR(x) ((const __attribute__((address_space(1))) unsigned int*)(x))

__device__ __forceinline__ unsigned short f2bf(float f) {
    unsigned int u = __float_as_uint(f);
    unsigned int r = (u + 0x7FFFu + ((u >> 16) & 1u)) >> 16;
    return (unsigned short)r;
}
__device__ __forceinline__ unsigned char f2fp8(float f) {
    __hip_fp8_e4m3 v(f);
    return (unsigned char)v.__x;
}
__device__ __forceinline__ float fp82f(unsigned int u) {
    __hip_fp8_e4m3 v;
    v.__x = (__hip_fp8_storage_t)(u & 0xFF);
    return (float)v;
}

// ---------------------------------------------------------------------------
// Fused post-side prep (one read of post_spikes & post_trace):
//   out_post_trace = S + dp*T (fp32, native)
//   At[p][k]   = fp8(S^T)   k in [0,B)      (RAW spikes)
//   At[p][B+k] = fp8(T^T)                   (RAW trace — dp folded into s)
// ---------------------------------------------------------------------------
__global__ __launch_bounds__(256) void prep_post_kernel(
    const float* __restrict__ S, const float* __restrict__ T,
    float* __restrict__ traceOut, unsigned char* __restrict__ At,
    int C, int K2, int Bsz, float dp)
{
    __shared__ float sT[64][65];
    __shared__ float tT[64][65];
    const int t = threadIdx.x;
    const int r0 = blockIdx.y * 64, c0 = blockIdx.x * 64;
#pragma unroll
    for (int i = 0; i < 4; ++i) {
        int rl = (t >> 4) + i * 16;
        int cl = (t & 15) * 4;
        size_t g = (size_t)(r0 + rl) * C + c0 + cl;
        float4 s4 = *(const float4*)&S[g];
        float4 t4 = *(const float4*)&T[g];
        float4 o;
        o.x = fmaf(t4.x, dp, s4.x); o.y = fmaf(t4.y, dp, s4.y);
        o.z = fmaf(t4.z, dp, s4.z); o.w = fmaf(t4.w, dp, s4.w);
        *(float4*)&traceOut[g] = o;
        sT[rl][cl + 0] = s4.x; sT[rl][cl + 1] = s4.y;
        sT[rl][cl + 2] = s4.z; sT[rl][cl + 3] = s4.w;
        tT[rl][cl + 0] = t4.x; tT[rl][cl + 1] = t4.y;
        tT[rl][cl + 2] = t4.z; tT[rl][cl + 3] = t4.w;
    }
    __syncthreads();
#pragma unroll
    for (int i = 0; i < 4; ++i) {
        int cl = (t >> 4) + i * 16;
        int rl = (t & 15) * 4;
        uchar4 a, b;
        a.x = f2fp8(sT[rl + 0][cl]); a.y = f2fp8(sT[rl + 1][cl]);
        a.z = f2fp8(sT[rl + 2][cl]); a.w = f2fp8(sT[rl + 3][cl]);
        b.x = f2fp8(tT[rl + 0][cl]); b.y = f2fp8(tT[rl + 1][cl]);
        b.z = f2fp8(tT[rl + 2][cl]); b.w = f2fp8(tT[rl + 3][cl]);
        *(uchar4*)&At[(size_t)(c0 + cl) * K2 + r0 + rl] = a;
        *(uchar4*)&At[(size_t)(c0 + cl) * K2 + Bsz + r0 + rl] = b;
    }
}

// ---------------------------------------------------------------------------
// Fused pre-side prep:
//   out_pre_trace = S + dp*T (fp32, native);  preBf = bf16(S) (native)
//   Bt[q][k]   = fp8(T^T)       (RAW pre_trace)
//   Bt[q][B+k] = fp8(-S^T)      (negated pre_spikes — sign folded)
// ---------------------------------------------------------------------------
__global__ __launch_bounds__(256) void prep_pre_kernel(
    const float* __restrict__ S, const float* __restrict__ T,
    float* __restrict__ traceOut, unsigned char* __restrict__ Bt,
    unsigned short* __restrict__ preBf,
    int C, int K2, int Bsz, float dp)
{
    __shared__ float sT[64][65];
    __shared__ float tT[64][65];
    const int t = threadIdx.x;
    const int r0 = blockIdx.y * 64, c0 = blockIdx.x * 64;
#pragma unroll
    for (int i = 0; i < 4; ++i) {
        int rl = (t >> 4) + i * 16;
        int cl = (t & 15) * 4;
        size_t g = (size_t)(r0 + rl) * C + c0 + cl;
        float4 s4 = *(const float4*)&S[g];
        float4 t4 = *(const float4*)&T[g];
        float4 o;
        o.x = fmaf(t4.x, dp, s4.x); o.y = fmaf(t4.y, dp, s4.y);
        o.z = fmaf(t4.z, dp, s4.z); o.w = fmaf(t4.w, dp, s4.w);
        *(float4*)&traceOut[g] = o;
        ushort4 pb = { f2bf(s4.x), f2bf(s4.y), f2bf(s4.z), f2bf(s4.w) };
        *(ushort4*)&preBf[g] = pb;
        sT[rl][cl + 0] = s4.x; sT[rl][cl + 1] = s4.y;
        sT[rl][cl + 2] = s4.z; sT[rl][cl + 3] = s4.w;
        tT[rl][cl + 0] = t4.x; tT[rl][cl + 1] = t4.y;
        tT[rl][cl + 2] = t4.z; tT[rl][cl + 3] = t4.w;
    }
    __syncthreads();
#pragma unroll
    for (int i = 0; i < 4; ++i) {
        int cl = (t >> 4) + i * 16;
        int rl = (t & 15) * 4;
        uchar4 a, b;
        a.x = f2fp8(tT[rl + 0][cl]); a.y = f2fp8(tT[rl + 1][cl]);
        a.z = f2fp8(tT[rl + 2][cl]); a.w = f2fp8(tT[rl + 3][cl]);
        b.x = f2fp8(-sT[rl + 0][cl]); b.y = f2fp8(-sT[rl + 1][cl]);
        b.z = f2fp8(-sT[rl + 2][cl]); b.w = f2fp8(-sT[rl + 3][cl]);
        *(uchar4*)&Bt[(size_t)(c0 + cl) * K2 + r0 + rl] = a;
        *(uchar4*)&Bt[(size_t)(c0 + cl) * K2 + Bsz + r0 + rl] = b;
    }
}

// ---------------------------------------------------------------------------
// Rate EMA from fp8-transposed post_spikes rows (At, k-contiguous).
// ---------------------------------------------------------------------------
__global__ __launch_bounds__(256) void rate_kernel(
    const unsigned char* __restrict__ At, const float* __restrict__ rr,
    float* __restrict__ new_rate, int K2, int Bsz)
{
    const int w = threadIdx.x >> 6, l = threadIdx.x & 63;
    const int p = blockIdx.x * 4 + w;
    const unsigned char* row = At + (size_t)p * K2;
    float s = 0.f;
    for (int k = l * 16; k < Bsz; k += 1024) {
        int4v v = *(const int4v*)&row[k];
#pragma unroll
        for (int wd = 0; wd < 4; ++wd) {
            unsigned int u = (unsigned int)v[wd];
            s += fp82f(u) + fp82f(u >> 8) + fp82f(u >> 16) + fp82f(u >> 24);
        }
    }
#pragma unroll
    for (int off = 32; off > 0; off >>= 1) s += __shfl_xor(s, off, 64);
    if (l == 0)
        new_rate[p] = rr[p] * 0.99f + 0.01f * (s / (float)Bsz);
}

// ---------------------------------------------------------------------------
// MX-fp8 dw GEMM (REVERTED to the R2 version — best measured, 69.4us).
// 128x128 tile, BK=128, mfma_scale_f32_16x16x128_f8f6f4, unit e8m0 scales.
// XOR-swizzled LDS; 2-phase double-buffered K-loop; coalesced epilogue via
// LDS f32 tile (Wold read + homeo + clip + dual-format store in epilogue).
// ---------------------------------------------------------------------------
__global__ __launch_bounds__(256) void dw_fp8_kernel(
    const unsigned char* __restrict__ A, const unsigned char* __restrict__ B,
    int K, int N, float s,
    const float* __restrict__ Wold, const float* __restrict__ rr,
    float* __restrict__ outF, unsigned short* __restrict__ outBf)
{
    constexpr int BM = 128, BN = 128, BK = 128;
    __shared__ unsigned char smem[65536];   // 2x(lA 16K) + 2x(lB 16K) | f32 out tile

    const int t = threadIdx.x;
    const int l = t & 63;
    const int w = t >> 6;
    const int wm = w >> 1, wn = w & 1;
    const int bm = blockIdx.y, bn = blockIdx.x;

    floatx4 acc[4][4] = {};

    auto stage = [&](int buf, int k0) {
        unsigned char* la = smem + buf * 16384;
        unsigned char* lb = smem + 32768 + buf * 16384;
#pragma unroll
        for (int i = 0; i < 4; ++i) {
            int ci = i * 256 + t;            // 16B chunk index (lane-linear)
            int r = ci >> 3, sc = ci & 7;
            int g = sc ^ (r & 7);            // swizzled source sub-chunk
            const unsigned char* gpA = A + (size_t)(bm * BM + r) * K + k0 + g * 16;
            __builtin_amdgcn_global_load_lds(GLB_PTR(gpA),
                LDS_PTR(la + ci * 16), 16, 0, 0);
            const unsigned char* gpB = B + (size_t)(bn * BN + r) * K + k0 + g * 16;
            __builtin_amdgcn_global_load_lds(GLB_PTR(gpB),
                LDS_PTR(lb + ci * 16), 16, 0, 0);
        }
    };

    stage(0, 0);
    __syncthreads();                 // prologue drain

    const int nT = K / BK;
    int cur = 0;
    for (int tt = 0; tt < nT; ++tt) {
        if (tt + 1 < nT) stage(cur ^ 1, (tt + 1) * BK);   // prefetch next tile

        const unsigned char* la = smem + cur * 16384;
        const unsigned char* lb = smem + 32768 + cur * 16384;
        const int c = l >> 4;      // k-quad: covers k bytes [c*32, c*32+32)
        const int m = l & 15;
        int8v af[4], bf[4];
#pragma unroll
        for (int i = 0; i < 4; ++i) {
            int ra = wm * 64 + i * 16 + m;
            int s0 = (2 * c) ^ (ra & 7), s1 = (2 * c + 1) ^ (ra & 7);
            int4v lo = *(const int4v*)&la[ra * BK + s0 * 16];
            int4v hi = *(const int4v*)&la[ra * BK + s1 * 16];
            af[i][0] = lo[0]; af[i][1] = lo[1]; af[i][2] = lo[2]; af[i][3] = lo[3];
            af[i][4] = hi[0]; af[i][5] = hi[1]; af[i][6] = hi[2]; af[i][7] = hi[3];
        }
#pragma unroll
        for (int j = 0; j < 4; ++j) {
            int rb = wn * 64 + j * 16 + m;
            int s0 = (2 * c) ^ (rb & 7), s1 = (2 * c + 1) ^ (rb & 7);
            int4v lo = *(const int4v*)&lb[rb * BK + s0 * 16];
            int4v hi = *(const int4v*)&lb[rb * BK + s1 * 16];
            bf[j][0] = lo[0]; bf[j][1] = lo[1]; bf[j][2] = lo[2]; bf[j][3] = lo[3];
            bf[j][4] = hi[0]; bf[j][5] = hi[1]; bf[j][6] = hi[2]; bf[j][7] = hi[3];
        }
#pragma unroll
        for (int i = 0; i < 4; ++i)
#pragma unroll
            for (int j = 0; j < 4; ++j)
                acc[i][j] = __builtin_amdgcn_mfma_scale_f32_16x16x128_f8f6f4(
                    af[i], bf[j], acc[i][j], 0, 0, 0, 0x7f, 0, 0x7f);

        asm volatile("s_waitcnt vmcnt(0)" ::: "memory");
        __builtin_amdgcn_s_barrier();
        cur ^= 1;
    }

    // ---- coalesced epilogue: acc -> LDS f32 tile -> row-major global ----
    __syncthreads();
    float* sOut = (float*)smem;      // 128 x 128 f32 = 64KB
#pragma unroll
    for (int i = 0; i < 4; ++i)
#pragma unroll
        for (int r = 0; r < 4; ++r) {
            const int row = wm * 64 + i * 16 + (l >> 4) * 4 + r;
#pragma unroll
            for (int j = 0; j < 4; ++j) {
                const int col = wn * 64 + j * 16 + (l & 15);
                sOut[row * 128 + col] = acc[i][j][r];
            }
        }
    __syncthreads();

    const int pBase = bm * BM;
    const int qBase = bn * BN;
#pragma unroll
    for (int k = 0; k < 16; ++k) {
        const int ci = k * 256 + t;          // float4 chunk index 0..4095
        const int row = ci >> 5;             // 0..127
        const int cc = (ci & 31) * 4;        // 0..124
        const int p = pBase + row;
        const int q = qBase + cc;
        const size_t idx = (size_t)p * N + q;
        float4 a4 = *(const float4*)&sOut[ci * 4];
        float4 w4 = *(const float4*)&Wold[idx];
        const float hp = -0.001f * (rr[p] - 0.1f);
        float4 v;
        v.x = fminf(fmaxf(fmaf(s, a4.x, w4.x + hp), 0.f), 1.f);
        v.y = fminf(fmaxf(fmaf(s, a4.y, w4.y + hp), 0.f), 1.f);
        v.z = fminf(fmaxf(fmaf(s, a4.z, w4.z + hp), 0.f), 1.f);
        v.w = fminf(fmaxf(fmaf(s, a4.w, w4.w + hp), 0.f), 1.f);
        *(float4*)&outF[idx] = v;
        ushort4 b4 = { f2bf(v.x), f2bf(v.y), f2bf(v.z), f2bf(v.w) };
        *(ushort4*)&outBf[idx] = b4;
    }
}

// ---------------------------------------------------------------------------
// BT-form bf16 MFMA GEMM (current = pre @ W^T).
// R4: 512 threads / 8 waves (2x4 wave grid), 128x128 tile, BK=128.
// Grid is pinned at 256 blocks (M=1024), so LDS is free: 128KB double-buffer,
// 32 MFMA/wave per K-step (was 16), 32 K-steps (was 64) -> 4x compute per
// barrier-pair, 2x waves/CU. Bijective chunk-XOR swizzle over 16-chunk rows
// (g = sc ^ (r&15)) applied identically on stage and read (rule #21).
// Coalesced epilogue via LDS f32 tile.
// ---------------------------------------------------------------------------
__global__ __launch_bounds__(512) void mfma_gemm_bt(
    const unsigned short* __restrict__ A,
    const unsigned short* __restrict__ Bm,
    int K, int N, float* __restrict__ outF)
{
    constexpr int BM = 128, BN = 128, BK = 128;
    __shared__ unsigned char smem[131072];  // 2 bufs x (lA 32K + lB 32K)

    const int t = threadIdx.x;
    const int l = t & 63;
    const int w = t >> 6;                   // 0..7
    const int wm = w >> 2, wn = w & 3;      // 2 row-halves x 4 col-quarters
    const int bm = blockIdx.y, bn = blockIdx.x;

    floatx4 acc[4][2] = {};                 // per wave: 64 rows x 32 cols

    auto stage = [&](int buf, int k0) {
        unsigned short* la = (unsigned short*)(smem + buf * 65536);
        unsigned short* lb = (unsigned short*)(smem + buf * 65536 + 32768);
#pragma unroll
        for (int i = 0; i < 4; ++i) {
            int ci = i * 512 + t;            // 16B chunk 0..2047; 16 chunks/row
            int r = ci >> 4, sc = ci & 15;
            int g = sc ^ (r & 15);           // swizzled source sub-chunk
            const unsigned short* gpA =
                A + (size_t)(bm * BM + r) * K + k0 + g * 8;
            __builtin_amdgcn_global_load_lds(GLB_PTR(gpA),
                LDS_PTR(la + ci * 8), 16, 0, 0);
            const unsigned short* gpB =
                Bm + (size_t)(bn * BN + r) * K + k0 + g * 8;
            __builtin_amdgcn_global_load_lds(GLB_PTR(gpB),
                LDS_PTR(lb + ci * 8), 16, 0, 0);
        }
    };

    stage(0, 0);
    __syncthreads();                 // prologue drain

    const int nT = K / BK;
    int cur = 0;
    for (int tt = 0; tt < nT; ++tt) {
        if (tt + 1 < nT) stage(cur ^ 1, (tt + 1) * BK);   // prefetch next tile

        const unsigned short* la = (const unsigned short*)(smem + cur * 65536);
        const unsigned short* lb = (const unsigned short*)(smem + cur * 65536 + 32768);
        const int q = l >> 4;      // 16B chunk within 64B k-slice
        const int m = l & 15;
#pragma unroll
        for (int ks = 0; ks < 4; ++ks) {
            short8 af[4], bf[2];
            const int c2 = ks * 4 + q;       // chunk 0..15
#pragma unroll
            for (int i = 0; i < 4; ++i) {
                int ra = wm * 64 + i * 16 + m;
                af[i] = *(const short8*)&la[ra * BK + ((c2 ^ (ra & 15)) * 8)];
            }
#pragma unroll
            for (int j = 0; j < 2; ++j) {
                int rb = wn * 32 + j * 16 + m;
                bf[j] = *(const short8*)&lb[rb * BK + ((c2 ^ (rb & 15)) * 8)];
            }
#pragma unroll
            for (int i = 0; i < 4; ++i)
#pragma unroll
                for (int j = 0; j < 2; ++j)
                    acc[i][j] = __builtin_amdgcn_mfma_f32_16x16x32_bf16(
                        af[i], bf[j], acc[i][j], 0, 0, 0);
        }

        asm volatile("s_waitcnt vmcnt(0)" ::: "memory");
        __builtin_amdgcn_s_barrier();
        cur ^= 1;
    }

    // ---- coalesced epilogue ----
    __syncthreads();
    float* sOut = (float*)smem;      // 128 x 128 f32 = 64KB (fits in 128KB)
#pragma unroll
    for (int i = 0; i < 4; ++i)
#pragma unroll
        for (int r = 0; r < 4; ++r) {
            const int row = wm * 64 + i * 16 + (l >> 4) * 4 + r;
#pragma unroll
            for (int j = 0; j < 2; ++j) {
                const int col = wn * 32 + j * 16 + (l & 15);
                sOut[row * 128 + col] = acc[i][j][r];
            }
        }
    __syncthreads();

    const int pBase = bm * BM;
    const int qBase = bn * BN;
#pragma unroll
    for (int k = 0; k < 8; ++k) {
        const int ci = k * 512 + t;          // float4 chunk 0..4095
        const int row = ci >> 5;             // 0..127
        const int cc = (ci & 31) * 4;
        float4 v = *(const float4*)&sOut[ci * 4];
        *(float4*)&outF[(size_t)(pBase + row) * N + qBase + cc] = v;
    }
}

// ---------------------------------------------------------------------------
extern "C" void kernel_launch(void* const* d_in, const int* in_sizes, int n_in,
                              void* d_out, int out_size, void* d_ws, size_t ws_size,
                              hipStream_t stream)
{
    const float* pre_spikes   = (const float*)d_in[0];
    const float* post_spikes  = (const float*)d_in[1];
    const float* weights      = (const float*)d_in[2];
    const float* pre_trace    = (const float*)d_in[3];
    const float* post_trace   = (const float*)d_in[4];
    const float* running_rate = (const float*)d_in[5];

    const int POST = in_sizes[5];
    const int PRE  = in_sizes[2] / POST;
    const int Bsz  = in_sizes[0] / PRE;
    const int K2   = 2 * Bsz;

    const size_t nCur   = (size_t)Bsz * POST;
    const size_t nW     = (size_t)POST * PRE;
    const size_t nPreT  = (size_t)Bsz * PRE;
    const size_t nPostT = (size_t)Bsz * POST;

    float* out_current    = (float*)d_out;
    float* out_weights    = out_current + nCur;
    float* out_pre_trace  = out_weights + nW;
    float* out_post_trace = out_pre_trace + nPreT;
    float* out_rate       = out_post_trace + nPostT;

    unsigned char* At     = (unsigned char*)d_ws;        // (POST x K2) fp8
    unsigned char* Bt     = At + (size_t)POST * K2;      // (PRE  x K2) fp8
    unsigned short* preBf = (unsigned short*)(Bt + (size_t)PRE * K2); // (B x PRE) bf16
    unsigned short* wBf   = preBf + nPreT;               // (POST x PRE) bf16

    const float dp = 0.95122942450071400910f;            // exp(-1/20)
    const float s  = dp * (0.01f / (float)Bsz);          // A+/-. * dp / B

    // 1) fused prep: traces + fp8 GEMM operands (one read per input)
    prep_post_kernel<<<dim3(POST / 64, Bsz / 64), 256, 0, stream>>>(
        post_spikes, post_trace, out_post_trace, At, POST, K2, Bsz, dp);
    prep_pre_kernel<<<dim3(PRE / 64, Bsz / 64), 256, 0, stream>>>(
        pre_spikes, pre_trace, out_pre_trace, Bt, preBf, PRE, K2, Bsz, dp);

    // 2) rate EMA
    rate_kernel<<<POST / 4, 256, 0, stream>>>(
        At, running_rate, out_rate, K2, Bsz);

    // 3) dw GEMM in MX-fp8 (M=POST, N=PRE, K=2B) + fused w/homeo/clip
    dw_fp8_kernel<<<dim3(PRE / 128, POST / 128), 256, 0, stream>>>(
        At, Bt, K2, PRE, s, weights, running_rate, out_weights, wBf);

    // 4) current GEMM bf16 (M=B, N=POST, K=PRE): pre_spikes @ new_w^T
    mfma_gemm_bt<<<dim3(POST / 128, Bsz / 128), 512, 0, stream>>>(
        preBf, wBf, PRE, POST, out_current);
}